// Round 8
// baseline (225.166 us; speedup 1.0000x reference)
//
#include <hip/hip_runtime.h>
#include <math.h>

// MambaBlock on MI355X. All dense contractions: bf16 MFMA 16x16x32, fp32 acc,
// 128x128 tile (wave-tile 64x64), BK=32, 3-buffer LDS pipeline with counted
// s_waitcnt vmcnt(N) + raw s_barrier, split-K (grid z) -> fp32 partials ->
// small reduce kernels (bias/act/cast). Scan: chunk-parallel 3-phase.
// Workspace compacted to 46.75 MB (round-6 proven envelope) via lifetime aliasing.

#define LL 1024
#define DD 1024
#define NS 16
#define CCH 16      // scan chunks
#define CLEN 64     // 1024 / CCH

typedef short     bf16x8_t __attribute__((ext_vector_type(8)));
typedef float     f32x4_t  __attribute__((ext_vector_type(4)));
typedef unsigned short u16x4_t __attribute__((ext_vector_type(4)));
typedef unsigned short u16x8_t __attribute__((ext_vector_type(8)));

__device__ __forceinline__ float silu_f(float x) { return x / (1.f + expf(-x)); }
__device__ __forceinline__ float softplus_f(float x) {
  return fmaxf(x, 0.f) + log1pf(expf(-fabsf(x)));
}
__device__ __forceinline__ unsigned short f2bf(float f) {  // RNE
  unsigned int u = __float_as_uint(f);
  u += 0x7fffu + ((u >> 16) & 1u);
  return (unsigned short)(u >> 16);
}

template<int N> __device__ __forceinline__ void s_wait_vmcnt() {
  asm volatile("s_waitcnt vmcnt(%0)" :: "n"(N) : "memory");
}
__device__ __forceinline__ void raw_barrier() {
  asm volatile("s_barrier" ::: "memory");
}

// ---------------- conversion / prep kernels ----------------
__global__ __launch_bounds__(256) void castk(const float* __restrict__ in,
                                             unsigned short* __restrict__ out, int n) {
  int i = (blockIdx.x * 256 + threadIdx.x) * 4;
  if (i >= n) return;
  float4 v = *(const float4*)(in + i);
  u16x4_t o; o[0] = f2bf(v.x); o[1] = f2bf(v.y); o[2] = f2bf(v.z); o[3] = f2bf(v.w);
  *(u16x4_t*)(out + i) = o;
}

// out[d][k] = W[k][d]  (1024x1024), fp32 -> bf16  (rows 0..1023 of wcomb)
__global__ __launch_bounds__(256) void tcastk(const float* __restrict__ W,
                                              unsigned short* __restrict__ out) {
  __shared__ float T[64][65];
  const int t = threadIdx.x;
  const int r = t >> 2, cq = (t & 3) << 4;
  const int d0 = blockIdx.x * 64, k0 = blockIdx.y * 64;
  #pragma unroll
  for (int c = 0; c < 16; c += 4) {
    float4 v = *(const float4*)&W[(size_t)(k0 + r) * DD + d0 + cq + c];
    T[r][cq + c + 0] = v.x; T[r][cq + c + 1] = v.y;
    T[r][cq + c + 2] = v.z; T[r][cq + c + 3] = v.w;
  }
  __syncthreads();
  u16x8_t o0, o1;
  #pragma unroll
  for (int j = 0; j < 8; ++j) o0[j] = f2bf(T[cq + j][r]);
  #pragma unroll
  for (int j = 0; j < 8; ++j) o1[j] = f2bf(T[cq + 8 + j][r]);
  *(u16x8_t*)&out[(size_t)(d0 + r) * DD + k0 + cq] = o0;
  *(u16x8_t*)&out[(size_t)(d0 + r) * DD + k0 + cq + 8] = o1;
}

// Rows 1024..1151 of wcomb: [W_B^T(16); W_C^T(16); zeros(96)], bf16.
__global__ __launch_bounds__(256) void bct_cast(const float* __restrict__ WB,
                                                const float* __restrict__ WC,
                                                unsigned short* __restrict__ wcomb) {
  const int b = blockIdx.x;         // 0..127 -> row 1024+b
  const int k = threadIdx.x * 4;
  u16x4_t o;
  if (b < 32) {
    const float* W = (b < 16) ? WB : WC;
    const int n = b & 15;
    #pragma unroll
    for (int j = 0; j < 4; ++j) o[j] = f2bf(W[(size_t)(k + j) * NS + n]);
  } else {
    o[0] = o[1] = o[2] = o[3] = 0;
  }
  *(u16x4_t*)&wcomb[(size_t)(1024 + b) * DD + k] = o;
}

// XshT[w][i*3+k] = xm[i][w-1+k] (zero-padded), bf16 -> bf16. out is [1024][3072].
__global__ __launch_bounds__(256) void build_xsht(const unsigned short* __restrict__ xm,
                                                  unsigned short* __restrict__ out) {
  __shared__ unsigned short Xs[64][66];
  const int t = threadIdx.x;
  const int w0 = blockIdx.x * 64, i0 = blockIdx.y * 64;
  {
    const int r = t >> 2, cq = (t & 3) << 4;
    #pragma unroll
    for (int c = 0; c < 16; c += 4) {
      u16x4_t v = *(const u16x4_t*)&xm[(size_t)(i0 + r) * DD + w0 + cq + c];
      Xs[r][1 + cq + c + 0] = v[0]; Xs[r][1 + cq + c + 1] = v[1];
      Xs[r][1 + cq + c + 2] = v[2]; Xs[r][1 + cq + c + 3] = v[3];
    }
  }
  if (t < 64)                 Xs[t][0]       = (w0 > 0)        ? xm[(size_t)(i0 + t) * DD + w0 - 1]  : (unsigned short)0;
  else if (t < 128) { int r = t - 64; Xs[r][65] = (w0 + 64 < DD) ? xm[(size_t)(i0 + r) * DD + w0 + 64] : (unsigned short)0; }
  __syncthreads();
  const int wr = t >> 2, q = t & 3;
  unsigned short vals[48];
  #pragma unroll
  for (int ii = 0; ii < 16; ++ii)
    #pragma unroll
    for (int k = 0; k < 3; ++k)
      vals[ii * 3 + k] = Xs[q * 16 + ii][wr + k];
  #pragma unroll
  for (int s = 0; s < 6; ++s) {
    u16x8_t o;
    #pragma unroll
    for (int j = 0; j < 8; ++j) o[j] = vals[s * 8 + j];
    *(u16x8_t*)&out[(size_t)(w0 + wr) * 3072 + (size_t)i0 * 3 + q * 48 + s * 8] = o;
  }
}

// ------------- bf16 MFMA split-K GEMM: part[z] = A[M,K] @ B[N,K]^T -------------
// Tile 128x128, 4 waves (2x2) each 64x64 (4x4 fragments), BK=32.
// 3-buffer LDS; stage t+2 before compute t; counted vmcnt; raw barrier.
// Linear LDS dest; chunk ^ ((row>>1)&3) swizzle on source+read (involution).
__global__ __launch_bounds__(256) void gemm_sk(
    const unsigned short* __restrict__ A, const unsigned short* __restrict__ B,
    float* __restrict__ part, size_t sliceStride, int N, int K, int Ksl)
{
  constexpr int GI = 4;                  // glds per thread per stage
  __shared__ unsigned short s[3][256 * 32];
  const int tid  = threadIdx.x;
  const int lane = tid & 63;
  const int wv   = tid >> 6;
  const int wm   = wv >> 1, wn = wv & 1;
  const int m0 = blockIdx.y * 128, n0 = blockIdx.x * 128;
  const int wbase = tid & 192;  // wave-uniform
  const int koff = blockIdx.z * Ksl;

  f32x4_t acc[4][4];
  #pragma unroll
  for (int i = 0; i < 4; ++i)
    #pragma unroll
    for (int j = 0; j < 4; ++j)
      acc[i][j] = (f32x4_t)(0.f);

  auto stage = [&](int buf, int kbase) {
    #pragma unroll
    for (int it = 0; it < GI; ++it) {
      const int c   = (it << 8) + tid;          // per-lane chunk id
      const int r   = c >> 2;                   // LDS row (A rows then B rows)
      const int kcg = (c & 3) ^ ((r >> 1) & 3); // pre-swizzled source k-chunk
      const unsigned short* src = (r < 128)
          ? (A + (size_t)(m0 + r) * K + kbase + kcg * 8)
          : (B + (size_t)(n0 + r - 128) * K + kbase + kcg * 8);
      __builtin_amdgcn_global_load_lds(
          (const __attribute__((address_space(1))) void*)src,
          (__attribute__((address_space(3))) void*)(&s[buf][0] + (size_t)((it << 8) + wbase) * 8),
          16, 0, 0);
    }
  };

  const int NT = Ksl >> 5;
  stage(0, koff);
  stage(1, koff + 32);
  s_wait_vmcnt<GI>();   // buf0 complete; buf1 in flight
  raw_barrier();

  for (int t = 0; t < NT; ++t) {
    if (t + 2 < NT) stage((t + 2) % 3, koff + (t + 2) * 32);

    const unsigned short* sb = &s[t % 3][0];
    const int rl = lane & 15, kq = lane >> 4;
    bf16x8_t af[4], bfr[4];
    #pragma unroll
    for (int mi = 0; mi < 4; ++mi) {
      const int row = wm * 64 + mi * 16 + rl;
      const int ch  = row * 4 + (kq ^ ((row >> 1) & 3));
      af[mi] = *(const bf16x8_t*)(sb + (size_t)ch * 8);
    }
    #pragma unroll
    for (int ni = 0; ni < 4; ++ni) {
      const int row = 128 + wn * 64 + ni * 16 + rl;
      const int ch  = row * 4 + (kq ^ ((row >> 1) & 3));
      bfr[ni] = *(const bf16x8_t*)(sb + (size_t)ch * 8);
    }
    #pragma unroll
    for (int mi = 0; mi < 4; ++mi)
      #pragma unroll
      for (int ni = 0; ni < 4; ++ni)
        acc[mi][ni] = __builtin_amdgcn_mfma_f32_16x16x32_bf16(af[mi], bfr[ni], acc[mi][ni], 0, 0, 0);

    if (t + 1 < NT) {
      if (t + 2 < NT) s_wait_vmcnt<GI>();
      else            s_wait_vmcnt<0>();
      raw_barrier();
    }
  }

  float* pz = part + (size_t)blockIdx.z * sliceStride;
  const int rl = lane & 15, rg = lane >> 4;
  #pragma unroll
  for (int mi = 0; mi < 4; ++mi) {
    #pragma unroll
    for (int ni = 0; ni < 4; ++ni) {
      const int col = n0 + wn * 64 + ni * 16 + rl;
      #pragma unroll
      for (int j = 0; j < 4; ++j) {
        const int row = m0 + wm * 64 + mi * 16 + rg * 4 + j;
        pz[(size_t)row * N + col] = acc[mi][ni][j];
      }
    }
  }
}

// ---------------- split-K reduce kernels ----------------
// Sum SK slices, bias + act, store. N == 1024 fixed. One float4 per thread.
// ACT: 0 none, 2 softplus, 3 silu iff row>=1024, 4 softplus iff row<1024.
template<int SK, int ACT, bool O32, bool O16>
__global__ __launch_bounds__(256) void reduce_k(
    const float* __restrict__ part, size_t sliceStride,
    const float* __restrict__ bias,  // column bias or null
    float* __restrict__ C32, unsigned short* __restrict__ C16)
{
  const size_t idx = ((size_t)blockIdx.x * 256 + threadIdx.x) * 4;
  const int row = (int)(idx >> 10), col = (int)(idx & 1023);
  float4 s = *(const float4*)&part[idx];
  #pragma unroll
  for (int z = 1; z < SK; ++z) {
    const float4 p = *(const float4*)&part[(size_t)z * sliceStride + idx];
    s.x += p.x; s.y += p.y; s.z += p.z; s.w += p.w;
  }
  float v[4] = {s.x, s.y, s.z, s.w};
  if (bias) {
    const float4 bv = *(const float4*)&bias[col];
    v[0] += bv.x; v[1] += bv.y; v[2] += bv.z; v[3] += bv.w;
  }
  #pragma unroll
  for (int j = 0; j < 4; ++j) {
    if (ACT == 2) v[j] = softplus_f(v[j]);
    else if (ACT == 3) { if (row >= 1024) v[j] = silu_f(v[j]); }
    else if (ACT == 4) { if (row < 1024)  v[j] = softplus_f(v[j]); }
  }
  if (O32) { float4 o; o.x = v[0]; o.y = v[1]; o.z = v[2]; o.w = v[3];
             *(float4*)&C32[idx] = o; }
  if (O16) { u16x4_t o; o[0] = f2bf(v[0]); o[1] = f2bf(v[1]);
             o[2] = f2bf(v[2]); o[3] = f2bf(v[3]);
             *(u16x4_t*)&C16[idx] = o; }
}

// Conv reduce: sum 4 slices [1024][1024], +cb[row], silu; write xc16 [l][d]
// (row-major) AND xcT32 [d][l] (transposed via LDS tile).
__global__ __launch_bounds__(256) void reduce_conv_t(
    const float* __restrict__ part, const float* __restrict__ cb,
    unsigned short* __restrict__ xc16, float* __restrict__ xcT)
{
  __shared__ float T[64][65];
  const int t = threadIdx.x;
  const int r = t >> 4;          // 0..15
  const int cq = (t & 15) << 2;  // 0..60
  const int r0 = blockIdx.y * 64, c0 = blockIdx.x * 64;
  #pragma unroll
  for (int rr = 0; rr < 64; rr += 16) {
    const int row = r0 + r + rr;
    const size_t base = (size_t)row * 1024 + c0 + cq;
    float4 s = *(const float4*)&part[base];
    #pragma unroll
    for (int z = 1; z < 4; ++z) {
      const float4 p = *(const float4*)&part[(size_t)z * (1024 * 1024) + base];
      s.x += p.x; s.y += p.y; s.z += p.z; s.w += p.w;
    }
    const float b = cb[row];
    float v[4] = {silu_f(s.x + b), silu_f(s.y + b), silu_f(s.z + b), silu_f(s.w + b)};
    u16x4_t o16; o16[0] = f2bf(v[0]); o16[1] = f2bf(v[1]);
    o16[2] = f2bf(v[2]); o16[3] = f2bf(v[3]);
    *(u16x4_t*)&xc16[base] = o16;
    T[r + rr][cq + 0] = v[0]; T[r + rr][cq + 1] = v[1];
    T[r + rr][cq + 2] = v[2]; T[r + rr][cq + 3] = v[3];
  }
  __syncthreads();
  #pragma unroll
  for (int rr = 0; rr < 64; rr += 16) {
    float4 o;
    o.x = T[cq + 0][r + rr]; o.y = T[cq + 1][r + rr];
    o.z = T[cq + 2][r + rr]; o.w = T[cq + 3][r + rr];
    *(float4*)&xcT[(size_t)(c0 + r + rr) * LL + r0 + cq] = o;
  }
}

// ---------------- chunk-parallel selective scan ----------------
__global__ __launch_bounds__(256) void scan_p1(
    const float* __restrict__ deltaT, const float* __restrict__ xcT,
    const float* __restrict__ BT, const float* __restrict__ A_log,
    float* __restrict__ P, float* __restrict__ H)
{
  const int tid = threadIdx.x;
  const int n = tid & 15, dl = tid >> 4;
  const int d = blockIdx.y * 16 + dl;
  const int c = blockIdx.x;
  const int l0 = c * CLEN;
  const float Av = -expf(A_log[d * NS + n]);
  float h = 0.f, p = 1.f;
  for (int j = 0; j < CLEN; j += 4) {
    const float4 dv = *(const float4*)&deltaT[(size_t)d * LL + l0 + j];
    const float4 xv = *(const float4*)&xcT[(size_t)d * LL + l0 + j];
    const float4 bv = *(const float4*)&BT[(size_t)n * LL + l0 + j];
    const float dvu[4] = {dv.x, dv.y, dv.z, dv.w};
    const float xvu[4] = {xv.x, xv.y, xv.z, xv.w};
    const float bvu[4] = {bv.x, bv.y, bv.z, bv.w};
    #pragma unroll
    for (int u = 0; u < 4; ++u) {
      const float ab = expf(dvu[u] * Av);
      h = fmaf(ab, h, dvu[u] * xvu[u] * bvu[u]);
      p *= ab;
    }
  }
  const int idx = d * NS + n;
  P[(size_t)c * (DD * NS) + idx] = p;
  H[(size_t)c * (DD * NS) + idx] = h;
}

__global__ __launch_bounds__(256) void scan_p2(const float* __restrict__ P,
                                               const float* __restrict__ H,
                                               float* __restrict__ Hin) {
  const int idx = blockIdx.x * 256 + threadIdx.x;  // 0..16383
  float hin = 0.f;
  Hin[idx] = 0.f;
  #pragma unroll
  for (int c = 1; c < CCH; ++c) {
    hin = fmaf(P[(size_t)(c - 1) * (DD * NS) + idx], hin,
               H[(size_t)(c - 1) * (DD * NS) + idx]);
    Hin[(size_t)c * (DD * NS) + idx] = hin;
  }
}

__global__ __launch_bounds__(256) void scan_p3(
    const float* __restrict__ deltaT, const float* __restrict__ xcT,
    const float* __restrict__ BT, const float* __restrict__ CT,
    const float* __restrict__ Hin, const float* __restrict__ A_log,
    unsigned short* __restrict__ y16)
{
  const int tid = threadIdx.x;
  const int n = tid & 15, dl = tid >> 4;
  const int d = blockIdx.y * 16 + dl;
  const int c = blockIdx.x;
  const int l0 = c * CLEN;
  const float Av = -expf(A_log[d * NS + n]);
  float h = Hin[(size_t)c * (DD * NS) + d * NS + n];
  for (int j = 0; j < CLEN; j += 4) {
    const float4 dv = *(const float4*)&deltaT[(size_t)d * LL + l0 + j];
    const float4 xv = *(const float4*)&xcT[(size_t)d * LL + l0 + j];
    const float4 bv = *(const float4*)&BT[(size_t)n * LL + l0 + j];
    const float4 cv = *(const float4*)&CT[(size_t)n * LL + l0 + j];
    const float dvu[4] = {dv.x, dv.y, dv.z, dv.w};
    const float xvu[4] = {xv.x, xv.y, xv.z, xv.w};
    const float bvu[4] = {bv.x, bv.y, bv.z, bv.w};
    const float cvu[4] = {cv.x, cv.y, cv.z, cv.w};
    #pragma unroll
    for (int u = 0; u < 4; ++u) {
      const int l = l0 + j + u;
      const float ab = expf(dvu[u] * Av);
      h = fmaf(ab, h, dvu[u] * xvu[u] * bvu[u]);
      float contrib = h * cvu[u];
      contrib += __shfl_xor(contrib, 1);
      contrib += __shfl_xor(contrib, 2);
      contrib += __shfl_xor(contrib, 4);
      contrib += __shfl_xor(contrib, 8);
      if (n == 0) y16[(size_t)l * DD + d] = f2bf(contrib);
    }
  }
}

// ---------------- launch ----------------
extern "C" void kernel_launch(void* const* d_in, const int* in_sizes, int n_in,
                              void* d_out, int out_size, void* d_ws, size_t ws_size,
                              hipStream_t stream) {
  const float* x       = (const float*)d_in[0];
  const float* W_proj  = (const float*)d_in[1];
  const float* b_proj  = (const float*)d_in[2];
  const float* conv_w  = (const float*)d_in[3];
  const float* conv_b  = (const float*)d_in[4];
  const float* A_log   = (const float*)d_in[5];
  const float* W_delta = (const float*)d_in[6];
  const float* W_B     = (const float*)d_in[7];
  const float* W_C     = (const float*)d_in[8];
  float* out = (float*)d_out;

  // Workspace layout: 0.25MB-granular offsets, peak 46.75 MB (== round-6
  // proven envelope). Lifetime aliasing:
  //   [14.5,18.625) x16 (T0->T1)        then dcomb32 (T4->T5)
  //   [18.75,24.75) cw16 (T0->T3)       then y16/Pc/Hc/Hin (T5) + out116 (T6->T7)
  //   part slab reused by every GEMM stage.
  char* w = (char*)d_ws;
  const size_t QMB = 256 * 1024;  // 0.25 MB
  unsigned short* wp16    = (unsigned short*)(w);             // [0,2)
  unsigned short* pbuf    = (unsigned short*)(w + 8  * QMB);  // [2,6): xm16|xg16
  unsigned short* xm16    = pbuf;
  unsigned short* xg16    = pbuf + 1024 * 1024;
  unsigned short* wcomb16 = (unsigned short*)(w + 24 * QMB);  // [6,8.5) 1152 rows
  unsigned short* xc16    = (unsigned short*)(w + 34 * QMB);  // [8.5,10.5)
  float*          xcT32   = (float*)(w + 42 * QMB);           // [10.5,14.5)
  unsigned short* x16     = (unsigned short*)(w + 58 * QMB);  // [14.5,18.5)  T0->T1
  float*          dcomb32 = (float*)(w + 58 * QMB);           // [14.5,18.625) T4->T5
  float*          deltaT32= dcomb32;                          // rows 0..1023
  float*          BT32    = dcomb32 + (size_t)1024 * 1024;    // rows 1024..1039
  float*          CT32    = dcomb32 + (size_t)1040 * 1024;    // rows 1040..1055
  unsigned short* cw16    = (unsigned short*)(w + 75 * QMB);  // [18.75,24.75) T0->T3
  unsigned short* y16     = (unsigned short*)(w + 75 * QMB);  // [18.75,20.75) T5->T6
  float*          Pc      = (float*)(w + 83 * QMB);           // [20.75,21.75) T5
  float*          Hc      = (float*)(w + 87 * QMB);           // [21.75,22.75) T5
  float*          HinC    = (float*)(w + 91 * QMB);           // [22.75,23.75) T5
  unsigned short* out116  = (unsigned short*)(w + 87 * QMB);  // [21.75,23.75) T6->T7
  unsigned short* xsht    = (unsigned short*)(w + 99 * QMB);  // [24.75,30.75) T2->T3
  float*          part    = (float*)(w + 123 * QMB);          // [30.75,46.75)
  (void)ws_size;

  const dim3 blk(256);

  // casts / weight prep
  castk<<<dim3(2048), blk, 0, stream>>>(x, x16, 2 * 1024 * 1024);
  castk<<<dim3(1024), blk, 0, stream>>>(W_proj, wp16, 1024 * 1024);
  castk<<<dim3(3072), blk, 0, stream>>>(conv_w, cw16, 3 * 1024 * 1024);
  tcastk<<<dim3(16, 16), blk, 0, stream>>>(W_delta, wcomb16);   // rows 0..1023
  bct_cast<<<dim3(128), blk, 0, stream>>>(W_B, W_C, wcomb16);   // rows 1024..1151

  // T1 proj: p = x @ W_proj^T (+b, rows>=1024 silu in reduce)  SK=2, part 16MB
  gemm_sk<<<dim3(8, 16, 2), blk, 0, stream>>>(x16, wp16, part,
      (size_t)2048 * 1024, 1024, 1024, 512);
  reduce_k<2, 3, false, true><<<dim3(2048), blk, 0, stream>>>(
      part, (size_t)2048 * 1024, b_proj, nullptr, pbuf);
  // T2 shifted-transposed conv activations
  build_xsht<<<dim3(16, 16), blk, 0, stream>>>(xm16, xsht);
  // T3 conv implicit GEMM, K=3072, SK=4 (part 16MB); reduce: +cb, silu, xc16+xcT
  gemm_sk<<<dim3(8, 8, 4), blk, 0, stream>>>(cw16, xsht, part,
      (size_t)1024 * 1024, 1024, 3072, 768);
  reduce_conv_t<<<dim3(16, 16), blk, 0, stream>>>(part, conv_b, xc16, xcT32);
  // T4 combined delta/B/C: wcomb[1152] @ xc^T, SK=2 (part 9MB); softplus rows<1024
  gemm_sk<<<dim3(8, 9, 2), blk, 0, stream>>>(wcomb16, xc16, part,
      (size_t)1152 * 1024, 1024, 1024, 512);
  reduce_k<2, 4, true, false><<<dim3(1056), blk, 0, stream>>>(
      part, (size_t)1152 * 1024, nullptr, dcomb32, nullptr);
  // T5 chunk-parallel scan
  scan_p1<<<dim3(CCH, DD / 16), blk, 0, stream>>>(deltaT32, xcT32, BT32, A_log, Pc, Hc);
  scan_p2<<<dim3(64), blk, 0, stream>>>(Pc, Hc, HinC);
  scan_p3<<<dim3(CCH, DD / 16), blk, 0, stream>>>(deltaT32, xcT32, BT32, CT32, HinC, A_log, y16);
  // T6 out1 = y @ xg^T, SK=4 (part 16MB)
  gemm_sk<<<dim3(8, 8, 4), blk, 0, stream>>>(y16, xg16, part,
      (size_t)1024 * 1024, 1024, 1024, 256);
  reduce_k<4, 0, false, true><<<dim3(1024), blk, 0, stream>>>(
      part, (size_t)1024 * 1024, nullptr, nullptr, out116);
  // T7 out = out1 @ W_proj^T + b, SK=4 (part 16MB)
  gemm_sk<<<dim3(8, 8, 4), blk, 0, stream>>>(out116, wp16, part,
      (size_t)1024 * 1024, 1024, 1024, 256);
  reduce_k<4, 0, true, false><<<dim3(1024), blk, 0, stream>>>(
      part, (size_t)1024 * 1024, b_proj, out, nullptr);
}

// Round 12
// 203.316 us; speedup vs baseline: 1.1075x; 1.1075x over previous
//
#include <hip/hip_runtime.h>
#include <math.h>

// MambaBlock on MI355X. Dense contractions: bf16 MFMA 16x16x32, fp32 acc.
// GEMM: 64x64 tile, BK=64, 3-buffer LDS, counted s_waitcnt vmcnt + raw
// s_barrier (round-6 proven structure), + split-K SK=2 on the M=1024 GEMMs
// so grids reach 512+ blocks = 2 blocks/CU = 2 waves/SIMD (TLP).
// Scan: chunk-parallel 3-phase. Workspace peak 39.75 MB.

#define LL 1024
#define DD 1024
#define NS 16
#define CCH 16      // scan chunks
#define CLEN 64     // 1024 / CCH

typedef short     bf16x8_t __attribute__((ext_vector_type(8)));
typedef float     f32x4_t  __attribute__((ext_vector_type(4)));
typedef unsigned short u16x4_t __attribute__((ext_vector_type(4)));
typedef unsigned short u16x8_t __attribute__((ext_vector_type(8)));

__device__ __forceinline__ float silu_f(float x) { return x / (1.f + expf(-x)); }
__device__ __forceinline__ float softplus_f(float x) {
  return fmaxf(x, 0.f) + log1pf(expf(-fabsf(x)));
}
__device__ __forceinline__ unsigned short f2bf(float f) {  // RNE
  unsigned int u = __float_as_uint(f);
  u += 0x7fffu + ((u >> 16) & 1u);
  return (unsigned short)(u >> 16);
}

template<int N> __device__ __forceinline__ void s_wait_vmcnt() {
  asm volatile("s_waitcnt vmcnt(%0)" :: "n"(N) : "memory");
}
__device__ __forceinline__ void raw_barrier() {
  asm volatile("s_barrier" ::: "memory");
}

// ---------------- conversion / prep kernels ----------------
// One kernel casts x (2M), W_proj (1M), conv_w (3M) fp32->bf16.
// Block-uniform branch: each block spans 1024 elems; boundaries are multiples.
__global__ __launch_bounds__(256) void cast_all(
    const float* __restrict__ x, const float* __restrict__ wp,
    const float* __restrict__ cw, unsigned short* __restrict__ x16,
    unsigned short* __restrict__ wp16, unsigned short* __restrict__ cw16) {
  const size_t i = ((size_t)blockIdx.x * 256 + threadIdx.x) * 4;
  const float* in; unsigned short* out; size_t off;
  if (i < 2097152)      { in = x;  out = x16;  off = 0; }
  else if (i < 3145728) { in = wp; out = wp16; off = 2097152; }
  else                  { in = cw; out = cw16; off = 3145728; }
  const float4 v = *(const float4*)(in + (i - off));
  u16x4_t o; o[0] = f2bf(v.x); o[1] = f2bf(v.y); o[2] = f2bf(v.z); o[3] = f2bf(v.w);
  *(u16x4_t*)(out + (i - off)) = o;
}

// out[d][k] = W[k][d]  (1024x1024), fp32 -> bf16  (rows 0..1023 of wcomb)
__global__ __launch_bounds__(256) void tcastk(const float* __restrict__ W,
                                              unsigned short* __restrict__ out) {
  __shared__ float T[64][65];
  const int t = threadIdx.x;
  const int r = t >> 2, cq = (t & 3) << 4;
  const int d0 = blockIdx.x * 64, k0 = blockIdx.y * 64;
  #pragma unroll
  for (int c = 0; c < 16; c += 4) {
    float4 v = *(const float4*)&W[(size_t)(k0 + r) * DD + d0 + cq + c];
    T[r][cq + c + 0] = v.x; T[r][cq + c + 1] = v.y;
    T[r][cq + c + 2] = v.z; T[r][cq + c + 3] = v.w;
  }
  __syncthreads();
  u16x8_t o0, o1;
  #pragma unroll
  for (int j = 0; j < 8; ++j) o0[j] = f2bf(T[cq + j][r]);
  #pragma unroll
  for (int j = 0; j < 8; ++j) o1[j] = f2bf(T[cq + 8 + j][r]);
  *(u16x8_t*)&out[(size_t)(d0 + r) * DD + k0 + cq] = o0;
  *(u16x8_t*)&out[(size_t)(d0 + r) * DD + k0 + cq + 8] = o1;
}

// Rows 1024..1151 of wcomb: [W_B^T(16); W_C^T(16); zeros(96)], bf16.
__global__ __launch_bounds__(256) void bct_cast(const float* __restrict__ WB,
                                                const float* __restrict__ WC,
                                                unsigned short* __restrict__ wcomb) {
  const int b = blockIdx.x;         // 0..127 -> row 1024+b
  const int k = threadIdx.x * 4;
  u16x4_t o;
  if (b < 32) {
    const float* W = (b < 16) ? WB : WC;
    const int n = b & 15;
    #pragma unroll
    for (int j = 0; j < 4; ++j) o[j] = f2bf(W[(size_t)(k + j) * NS + n]);
  } else {
    o[0] = o[1] = o[2] = o[3] = 0;
  }
  *(u16x4_t*)&wcomb[(size_t)(1024 + b) * DD + k] = o;
}

// XshT[w][i*3+k] = xm[i][w-1+k] (zero-padded), bf16 -> bf16. out is [1024][3072].
__global__ __launch_bounds__(256) void build_xsht(const unsigned short* __restrict__ xm,
                                                  unsigned short* __restrict__ out) {
  __shared__ unsigned short Xs[64][66];
  const int t = threadIdx.x;
  const int w0 = blockIdx.x * 64, i0 = blockIdx.y * 64;
  {
    const int r = t >> 2, cq = (t & 3) << 4;
    #pragma unroll
    for (int c = 0; c < 16; c += 4) {
      u16x4_t v = *(const u16x4_t*)&xm[(size_t)(i0 + r) * DD + w0 + cq + c];
      Xs[r][1 + cq + c + 0] = v[0]; Xs[r][1 + cq + c + 1] = v[1];
      Xs[r][1 + cq + c + 2] = v[2]; Xs[r][1 + cq + c + 3] = v[3];
    }
  }
  if (t < 64)                 Xs[t][0]       = (w0 > 0)        ? xm[(size_t)(i0 + t) * DD + w0 - 1]  : (unsigned short)0;
  else if (t < 128) { int r = t - 64; Xs[r][65] = (w0 + 64 < DD) ? xm[(size_t)(i0 + r) * DD + w0 + 64] : (unsigned short)0; }
  __syncthreads();
  const int wr = t >> 2, q = t & 3;
  unsigned short vals[48];
  #pragma unroll
  for (int ii = 0; ii < 16; ++ii)
    #pragma unroll
    for (int k = 0; k < 3; ++k)
      vals[ii * 3 + k] = Xs[q * 16 + ii][wr + k];
  #pragma unroll
  for (int s = 0; s < 6; ++s) {
    u16x8_t o;
    #pragma unroll
    for (int j = 0; j < 8; ++j) o[j] = vals[s * 8 + j];
    *(u16x8_t*)&out[(size_t)(w0 + wr) * 3072 + (size_t)i0 * 3 + q * 48 + s * 8] = o;
  }
}

// ------------- bf16 MFMA GEMM: C = act(A[M,K] @ B[N,K]^T + bias) -------------
// 64x64 tile, BK=64, 4 waves (2x2) each 32x32 (2x2 frags, 8 MFMA/step).
// 3-buffer LDS; stage t+2 before compute t; counted vmcnt; raw barrier.
// Linear LDS dest; chunk ^ (row&7) swizzle on source+read (involution).
// PART: split-K slice blockIdx.z over Ksl columns -> fp32 partial (no act).
// ACT: 0 none, 1 silu, 2 softplus, 3 silu iff row>=1024, 4 softplus iff row<1024.
template<int ACT, bool BROW, bool O32, bool O16, bool PART>
__global__ __launch_bounds__(256) void gemm_bf16(
    const unsigned short* __restrict__ A, const unsigned short* __restrict__ B,
    const float* __restrict__ bias, float* __restrict__ C32,
    unsigned short* __restrict__ C16, int M, int N, int K, int Ksl,
    size_t sliceStride)
{
  constexpr int GI = 4;                  // glds per thread per stage
  __shared__ unsigned short s[3][128 * 64];
  const int tid  = threadIdx.x;
  const int lane = tid & 63;
  const int wv   = tid >> 6;
  const int wm   = wv >> 1, wn = wv & 1;
  const int m0 = blockIdx.y * 64, n0 = blockIdx.x * 64;
  const int wbase = tid & 192;  // wave-uniform
  const int koff = PART ? blockIdx.z * Ksl : 0;

  f32x4_t acc[2][2];
  #pragma unroll
  for (int i = 0; i < 2; ++i)
    #pragma unroll
    for (int j = 0; j < 2; ++j)
      acc[i][j] = (f32x4_t)(0.f);

  auto stage = [&](int buf, int kbase) {
    #pragma unroll
    for (int it = 0; it < GI; ++it) {
      const int c   = (it << 8) + tid;        // linear dest chunk id (0..1023)
      const int r   = c >> 3;                 // LDS row (64 A rows then 64 B rows)
      const int kcg = (c & 7) ^ (r & 7);      // pre-swizzled source k-chunk
      const unsigned short* src = (r < 64)
          ? (A + (size_t)(m0 + r) * K + kbase + kcg * 8)
          : (B + (size_t)(n0 + r - 64) * K + kbase + kcg * 8);
      __builtin_amdgcn_global_load_lds(
          (const __attribute__((address_space(1))) void*)src,
          (__attribute__((address_space(3))) void*)(&s[buf][0] + (size_t)((it << 8) + wbase) * 8),
          16, 0, 0);
    }
  };

  const int NT = Ksl >> 6;
  stage(0, koff);
  stage(1, koff + 64);
  s_wait_vmcnt<GI>();   // buf0 complete; buf1 in flight
  raw_barrier();

  for (int t = 0; t < NT; ++t) {
    if (t + 2 < NT) stage((t + 2) % 3, koff + (t + 2) * 64);

    const unsigned short* sb = &s[t % 3][0];
    const int rl = lane & 15, kq = lane >> 4;
    bf16x8_t af[2][2], bfr[2][2];
    #pragma unroll
    for (int mi = 0; mi < 2; ++mi) {
      const int row = wm * 32 + mi * 16 + rl;
      #pragma unroll
      for (int ks = 0; ks < 2; ++ks) {
        const int ch = row * 8 + ((ks * 4 + kq) ^ (row & 7));
        af[mi][ks] = *(const bf16x8_t*)(sb + (size_t)ch * 8);
      }
    }
    #pragma unroll
    for (int ni = 0; ni < 2; ++ni) {
      const int row = 64 + wn * 32 + ni * 16 + rl;
      #pragma unroll
      for (int ks = 0; ks < 2; ++ks) {
        const int ch = row * 8 + ((ks * 4 + kq) ^ (row & 7));
        bfr[ni][ks] = *(const bf16x8_t*)(sb + (size_t)ch * 8);
      }
    }
    #pragma unroll
    for (int mi = 0; mi < 2; ++mi)
      #pragma unroll
      for (int ni = 0; ni < 2; ++ni)
        #pragma unroll
        for (int ks = 0; ks < 2; ++ks)
          acc[mi][ni] = __builtin_amdgcn_mfma_f32_16x16x32_bf16(
              af[mi][ks], bfr[ni][ks], acc[mi][ni], 0, 0, 0);

    if (t + 1 < NT) {
      if (t + 2 < NT) s_wait_vmcnt<GI>();  // next buf ready, newest stays in flight
      else            s_wait_vmcnt<0>();
      raw_barrier();
    }
  }

  const int rl = lane & 15, rg = lane >> 4;
  float* outp = PART ? (C32 + (size_t)blockIdx.z * sliceStride) : C32;
  #pragma unroll
  for (int mi = 0; mi < 2; ++mi) {
    #pragma unroll
    for (int ni = 0; ni < 2; ++ni) {
      const int col = n0 + wn * 32 + ni * 16 + rl;
      #pragma unroll
      for (int j = 0; j < 4; ++j) {
        const int row = m0 + wm * 32 + mi * 16 + rg * 4 + j;
        float v = acc[mi][ni][j];
        if (PART) {
          outp[(size_t)row * N + col] = v;
        } else {
          if (bias) v += BROW ? bias[row] : bias[col];
          if (ACT == 1) v = silu_f(v);
          else if (ACT == 2) v = softplus_f(v);
          else if (ACT == 3) { if (row >= 1024) v = silu_f(v); }
          else if (ACT == 4) { if (row < 1024)  v = softplus_f(v); }
          if (O32) C32[(size_t)row * N + col] = v;
          if (O16) C16[(size_t)row * N + col] = f2bf(v);
        }
      }
    }
  }
}

// ---------------- split-K reduce kernels ----------------
// Sum SK slices, bias + act, store. N == 1024 fixed. One float4 per thread.
// ACT: 0 none, 2 softplus, 4 softplus iff row<1024.
template<int SK, int ACT, bool O32, bool O16>
__global__ __launch_bounds__(256) void reduce_k(
    const float* __restrict__ part, size_t sliceStride,
    const float* __restrict__ bias,  // column bias or null
    float* __restrict__ C32, unsigned short* __restrict__ C16)
{
  const size_t idx = ((size_t)blockIdx.x * 256 + threadIdx.x) * 4;
  const int row = (int)(idx >> 10), col = (int)(idx & 1023);
  float4 s = *(const float4*)&part[idx];
  #pragma unroll
  for (int z = 1; z < SK; ++z) {
    const float4 p = *(const float4*)&part[(size_t)z * sliceStride + idx];
    s.x += p.x; s.y += p.y; s.z += p.z; s.w += p.w;
  }
  float v[4] = {s.x, s.y, s.z, s.w};
  if (bias) {
    const float4 bv = *(const float4*)&bias[col];
    v[0] += bv.x; v[1] += bv.y; v[2] += bv.z; v[3] += bv.w;
  }
  #pragma unroll
  for (int j = 0; j < 4; ++j) {
    if (ACT == 2) v[j] = softplus_f(v[j]);
    else if (ACT == 4) { if (row < 1024) v[j] = softplus_f(v[j]); }
  }
  if (O32) { float4 o; o.x = v[0]; o.y = v[1]; o.z = v[2]; o.w = v[3];
             *(float4*)&C32[idx] = o; }
  if (O16) { u16x4_t o; o[0] = f2bf(v[0]); o[1] = f2bf(v[1]);
             o[2] = f2bf(v[2]); o[3] = f2bf(v[3]);
             *(u16x4_t*)&C16[idx] = o; }
}

// Conv reduce: sum SK slices [1024][1024], +cb[row], silu; write xc16 [l][d]
// AND xcT32 [d][l] (transposed via LDS tile).
template<int SK>
__global__ __launch_bounds__(256) void reduce_conv_t(
    const float* __restrict__ part, const float* __restrict__ cb,
    unsigned short* __restrict__ xc16, float* __restrict__ xcT)
{
  __shared__ float T[64][65];
  const int t = threadIdx.x;
  const int r = t >> 4;          // 0..15
  const int cq = (t & 15) << 2;  // 0..60
  const int r0 = blockIdx.y * 64, c0 = blockIdx.x * 64;
  #pragma unroll
  for (int rr = 0; rr < 64; rr += 16) {
    const int row = r0 + r + rr;
    const size_t base = (size_t)row * 1024 + c0 + cq;
    float4 s = *(const float4*)&part[base];
    #pragma unroll
    for (int z = 1; z < SK; ++z) {
      const float4 p = *(const float4*)&part[(size_t)z * (1024 * 1024) + base];
      s.x += p.x; s.y += p.y; s.z += p.z; s.w += p.w;
    }
    const float b = cb[row];
    float v[4] = {silu_f(s.x + b), silu_f(s.y + b), silu_f(s.z + b), silu_f(s.w + b)};
    u16x4_t o16; o16[0] = f2bf(v[0]); o16[1] = f2bf(v[1]);
    o16[2] = f2bf(v[2]); o16[3] = f2bf(v[3]);
    *(u16x4_t*)&xc16[base] = o16;
    T[r + rr][cq + 0] = v[0]; T[r + rr][cq + 1] = v[1];
    T[r + rr][cq + 2] = v[2]; T[r + rr][cq + 3] = v[3];
  }
  __syncthreads();
  #pragma unroll
  for (int rr = 0; rr < 64; rr += 16) {
    float4 o;
    o.x = T[cq + 0][r + rr]; o.y = T[cq + 1][r + rr];
    o.z = T[cq + 2][r + rr]; o.w = T[cq + 3][r + rr];
    *(float4*)&xcT[(size_t)(c0 + r + rr) * LL + r0 + cq] = o;
  }
}

// ---------------- chunk-parallel selective scan ----------------
__global__ __launch_bounds__(256) void scan_p1(
    const float* __restrict__ deltaT, const float* __restrict__ xcT,
    const float* __restrict__ BT, const float* __restrict__ A_log,
    float* __restrict__ P, float* __restrict__ H)
{
  const int tid = threadIdx.x;
  const int n = tid & 15, dl = tid >> 4;
  const int d = blockIdx.y * 16 + dl;
  const int c = blockIdx.x;
  const int l0 = c * CLEN;
  const float Av = -expf(A_log[d * NS + n]);
  float h = 0.f, p = 1.f;
  for (int j = 0; j < CLEN; j += 4) {
    const float4 dv = *(const float4*)&deltaT[(size_t)d * LL + l0 + j];
    const float4 xv = *(const float4*)&xcT[(size_t)d * LL + l0 + j];
    const float4 bv = *(const float4*)&BT[(size_t)n * LL + l0 + j];
    const float dvu[4] = {dv.x, dv.y, dv.z, dv.w};
    const float xvu[4] = {xv.x, xv.y, xv.z, xv.w};
    const float bvu[4] = {bv.x, bv.y, bv.z, bv.w};
    #pragma unroll
    for (int u = 0; u < 4; ++u) {
      const float ab = expf(dvu[u] * Av);
      h = fmaf(ab, h, dvu[u] * xvu[u] * bvu[u]);
      p *= ab;
    }
  }
  const int idx = d * NS + n;
  P[(size_t)c * (DD * NS) + idx] = p;
  H[(size_t)c * (DD * NS) + idx] = h;
}

__global__ __launch_bounds__(256) void scan_p2(const float* __restrict__ P,
                                               const float* __restrict__ H,
                                               float* __restrict__ Hin) {
  const int idx = blockIdx.x * 256 + threadIdx.x;  // 0..16383
  float hin = 0.f;
  Hin[idx] = 0.f;
  #pragma unroll
  for (int c = 1; c < CCH; ++c) {
    hin = fmaf(P[(size_t)(c - 1) * (DD * NS) + idx], hin,
               H[(size_t)(c - 1) * (DD * NS) + idx]);
    Hin[(size_t)c * (DD * NS) + idx] = hin;
  }
}

__global__ __launch_bounds__(256) void scan_p3(
    const float* __restrict__ deltaT, const float* __restrict__ xcT,
    const float* __restrict__ BT, const float* __restrict__ CT,
    const float* __restrict__ Hin, const float* __restrict__ A_log,
    unsigned short* __restrict__ y16)
{
  const int tid = threadIdx.x;
  const int n = tid & 15, dl = tid >> 4;
  const int d = blockIdx.y * 16 + dl;
  const int c = blockIdx.x;
  const int l0 = c * CLEN;
  const float Av = -expf(A_log[d * NS + n]);
  float h = Hin[(size_t)c * (DD * NS) + d * NS + n];
  for (int j = 0; j < CLEN; j += 4) {
    const float4 dv = *(const float4*)&deltaT[(size_t)d * LL + l0 + j];
    const float4 xv = *(const float4*)&xcT[(size_t)d * LL + l0 + j];
    const float4 bv = *(const float4*)&BT[(size_t)n * LL + l0 + j];
    const float4 cv = *(const float4*)&CT[(size_t)n * LL + l0 + j];
    const float dvu[4] = {dv.x, dv.y, dv.z, dv.w};
    const float xvu[4] = {xv.x, xv.y, xv.z, xv.w};
    const float bvu[4] = {bv.x, bv.y, bv.z, bv.w};
    const float cvu[4] = {cv.x, cv.y, cv.z, cv.w};
    #pragma unroll
    for (int u = 0; u < 4; ++u) {
      const int l = l0 + j + u;
      const float ab = expf(dvu[u] * Av);
      h = fmaf(ab, h, dvu[u] * xvu[u] * bvu[u]);
      float contrib = h * cvu[u];
      contrib += __shfl_xor(contrib, 1);
      contrib += __shfl_xor(contrib, 2);
      contrib += __shfl_xor(contrib, 4);
      contrib += __shfl_xor(contrib, 8);
      if (n == 0) y16[(size_t)l * DD + d] = f2bf(contrib);
    }
  }
}

// ---------------- launch ----------------
extern "C" void kernel_launch(void* const* d_in, const int* in_sizes, int n_in,
                              void* d_out, int out_size, void* d_ws, size_t ws_size,
                              hipStream_t stream) {
  const float* x       = (const float*)d_in[0];
  const float* W_proj  = (const float*)d_in[1];
  const float* b_proj  = (const float*)d_in[2];
  const float* conv_w  = (const float*)d_in[3];
  const float* conv_b  = (const float*)d_in[4];
  const float* A_log   = (const float*)d_in[5];
  const float* W_delta = (const float*)d_in[6];
  const float* W_B     = (const float*)d_in[7];
  const float* W_C     = (const float*)d_in[8];
  float* out = (float*)d_out;

  // Workspace: 0.25MB-granular offsets, peak 39.75 MB (< 46.75 proven).
  // Lifetime aliasing:
  //   [14.5,18.625) x16 (T0->T1) then dcomb32 (T4->T5)
  //   [18.75,24.75) cw16 (T0->T3) then y16 (T5->T6), Pc/Hc/Hin (T5),
  //                 out116 (T6->T7, over Hc+Hin)
  //   part slab [30.75,39.75) reused by every split-K GEMM stage.
  char* w = (char*)d_ws;
  const size_t QMB = 256 * 1024;  // 0.25 MB
  unsigned short* wp16    = (unsigned short*)(w);             // [0,2)
  unsigned short* pbuf    = (unsigned short*)(w + 8  * QMB);  // [2,6): xm16|xg16
  unsigned short* xm16    = pbuf;
  unsigned short* xg16    = pbuf + 1024 * 1024;
  unsigned short* wcomb16 = (unsigned short*)(w + 24 * QMB);  // [6,8.5) 1152 rows
  unsigned short* xc16    = (unsigned short*)(w + 34 * QMB);  // [8.5,10.5)
  float*          xcT32   = (float*)(w + 42 * QMB);           // [10.5,14.5)
  unsigned short* x16     = (unsigned short*)(w + 58 * QMB);  // [14.5,18.5)  T0->T1
  float*          dcomb32 = (float*)(w + 58 * QMB);           // [14.5,18.625) T4->T5
  float*          deltaT32= dcomb32;                          // rows 0..1023
  float*          BT32    = dcomb32 + (size_t)1024 * 1024;    // rows 1024..1039
  float*          CT32    = dcomb32 + (size_t)1040 * 1024;    // rows 1040..1055
  unsigned short* cw16    = (unsigned short*)(w + 75 * QMB);  // [18.75,24.75) T0->T3
  unsigned short* y16     = (unsigned short*)(w + 75 * QMB);  // [18.75,20.75) T5->T6
  float*          Pc      = (float*)(w + 83 * QMB);           // [20.75,21.75) T5
  float*          Hc      = (float*)(w + 87 * QMB);           // [21.75,22.75) T5
  float*          HinC    = (float*)(w + 91 * QMB);           // [22.75,23.75) T5
  unsigned short* out116  = (unsigned short*)(w + 87 * QMB);  // [21.75,23.75) T6->T7
  unsigned short* xsht    = (unsigned short*)(w + 99 * QMB);  // [24.75,30.75) T2->T3
  float*          part    = (float*)(w + 123 * QMB);          // [30.75,39.75)
  (void)ws_size;

  const dim3 blk(256);

  // T0 casts / weight prep (3 dispatches)
  cast_all<<<dim3(6144), blk, 0, stream>>>(x, W_proj, conv_w, x16, wp16, cw16);
  tcastk<<<dim3(16, 16), blk, 0, stream>>>(W_delta, wcomb16);   // rows 0..1023
  bct_cast<<<dim3(128), blk, 0, stream>>>(W_B, W_C, wcomb16);   // rows 1024..1151

  // T1 proj: p = x @ W_proj^T + b; rows>=1024 silu. Full K, 512 blocks.
  gemm_bf16<3, false, false, true, false><<<dim3(16, 32), blk, 0, stream>>>(
      x16, wp16, b_proj, nullptr, pbuf, 2048, 1024, 1024, 1024, 0);
  // T2 shifted-transposed conv activations
  build_xsht<<<dim3(16, 16), blk, 0, stream>>>(xm16, xsht);
  // T3 conv implicit GEMM, K=3072, SK=2 (512 blocks); reduce: +cb, silu, xc16+xcT
  gemm_bf16<0, false, true, false, true><<<dim3(16, 16, 2), blk, 0, stream>>>(
      cw16, xsht, nullptr, part, nullptr, 1024, 1024, 3072, 1536,
      (size_t)1024 * 1024);
  reduce_conv_t<2><<<dim3(16, 16), blk, 0, stream>>>(part, conv_b, xc16, xcT32);
  // T4 combined delta/B/C: wcomb[1152] @ xc^T, SK=2 (576 blocks); softplus rows<1024
  gemm_bf16<0, false, true, false, true><<<dim3(16, 18, 2), blk, 0, stream>>>(
      wcomb16, xc16, nullptr, part, nullptr, 1152, 1024, 1024, 512,
      (size_t)1152 * 1024);
  reduce_k<2, 4, true, false><<<dim3(1056), blk, 0, stream>>>(
      part, (size_t)1152 * 1024, nullptr, dcomb32, nullptr);
  // T5 chunk-parallel scan
  scan_p1<<<dim3(CCH, DD / 16), blk, 0, stream>>>(deltaT32, xcT32, BT32, A_log, Pc, Hc);
  scan_p2<<<dim3(64), blk, 0, stream>>>(Pc, Hc, HinC);
  scan_p3<<<dim3(CCH, DD / 16), blk, 0, stream>>>(deltaT32, xcT32, BT32, CT32, HinC, A_log, y16);
  // T6 out1 = y @ xg^T, SK=2 (512 blocks)
  gemm_bf16<0, false, true, false, true><<<dim3(16, 16, 2), blk, 0, stream>>>(
      y16, xg16, nullptr, part, nullptr, 1024, 1024, 1024, 512,
      (size_t)1024 * 1024);
  reduce_k<2, 0, false, true><<<dim3(1024), blk, 0, stream>>>(
      part, (size_t)1024 * 1024, nullptr, nullptr, out116);
  // T7 out = out1 @ W_proj^T + b, SK=2 (512 blocks)
  gemm_bf16<0, false, true, false, true><<<dim3(16, 16, 2), blk, 0, stream>>>(
      out116, wp16, nullptr, part, nullptr, 1024, 1024, 1024, 512,
      (size_t)1024 * 1024);
  reduce_k<2, 0, true, false><<<dim3(1024), blk, 0, stream>>>(
      part, (size_t)1024 * 1024, b_proj, out, nullptr);
}

// Round 14
// 192.901 us; speedup vs baseline: 1.1673x; 1.0540x over previous
//
#include <hip/hip_runtime.h>
#include <math.h>

// MambaBlock on MI355X. Dense contractions: bf16 MFMA 16x16x32, fp32 acc.
// GEMM: 64x64 tile, BK=64, 3-buffer LDS, counted s_waitcnt vmcnt + raw
// s_barrier (proven structure). Dispatch-count minimized: 10 dispatches
// (merged preps, fused epilogues, scan carry computed in-block).

#define LL 1024
#define DD 1024
#define NS 16
#define CCH 16      // scan chunks
#define CLEN 64     // 1024 / CCH

typedef short     bf16x8_t __attribute__((ext_vector_type(8)));
typedef float     f32x4_t  __attribute__((ext_vector_type(4)));
typedef unsigned short u16x4_t __attribute__((ext_vector_type(4)));
typedef unsigned short u16x8_t __attribute__((ext_vector_type(8)));

__device__ __forceinline__ float silu_f(float x) { return x / (1.f + expf(-x)); }
__device__ __forceinline__ float softplus_f(float x) {
  return fmaxf(x, 0.f) + log1pf(expf(-fabsf(x)));
}
__device__ __forceinline__ unsigned short f2bf(float f) {  // RNE
  unsigned int u = __float_as_uint(f);
  u += 0x7fffu + ((u >> 16) & 1u);
  return (unsigned short)(u >> 16);
}

template<int N> __device__ __forceinline__ void s_wait_vmcnt() {
  asm volatile("s_waitcnt vmcnt(%0)" :: "n"(N) : "memory");
}
__device__ __forceinline__ void raw_barrier() {
  asm volatile("s_barrier" ::: "memory");
}

// ---------------- merged prep kernel ----------------
// blocks [0,6144): cast x (2M), W_proj (1M), conv_w (3M) fp32->bf16 (flat).
// blocks [6144,6400): wcomb rows 0..1023 = W_delta^T (transpose-cast).
// blocks [6400,6528): wcomb rows 1024..1151 = [W_B^T; W_C^T; zeros].
__global__ __launch_bounds__(256) void prep_all(
    const float* __restrict__ x, const float* __restrict__ wp,
    const float* __restrict__ cw, const float* __restrict__ wd,
    const float* __restrict__ WB, const float* __restrict__ WC,
    unsigned short* __restrict__ x16, unsigned short* __restrict__ wp16,
    unsigned short* __restrict__ cw16, unsigned short* __restrict__ wcomb) {
  const int b = blockIdx.x;
  const int t = threadIdx.x;
  if (b < 6144) {
    const size_t i = ((size_t)b * 256 + t) * 4;
    const float* in; unsigned short* out; size_t off;
    if (i < 2097152)      { in = x;  out = x16;  off = 0; }
    else if (i < 3145728) { in = wp; out = wp16; off = 2097152; }
    else                  { in = cw; out = cw16; off = 3145728; }
    const float4 v = *(const float4*)(in + (i - off));
    u16x4_t o; o[0] = f2bf(v.x); o[1] = f2bf(v.y); o[2] = f2bf(v.z); o[3] = f2bf(v.w);
    *(u16x4_t*)(out + (i - off)) = o;
  } else if (b < 6400) {
    __shared__ float T[64][65];
    const int bi = b - 6144;
    const int d0 = (bi & 15) << 6, k0 = (bi >> 4) << 6;
    const int r = t >> 2, cq = (t & 3) << 4;
    #pragma unroll
    for (int c = 0; c < 16; c += 4) {
      float4 v = *(const float4*)&wd[(size_t)(k0 + r) * DD + d0 + cq + c];
      T[r][cq + c + 0] = v.x; T[r][cq + c + 1] = v.y;
      T[r][cq + c + 2] = v.z; T[r][cq + c + 3] = v.w;
    }
    __syncthreads();
    u16x8_t o0, o1;
    #pragma unroll
    for (int j = 0; j < 8; ++j) o0[j] = f2bf(T[cq + j][r]);
    #pragma unroll
    for (int j = 0; j < 8; ++j) o1[j] = f2bf(T[cq + 8 + j][r]);
    *(u16x8_t*)&wcomb[(size_t)(d0 + r) * DD + k0 + cq] = o0;
    *(u16x8_t*)&wcomb[(size_t)(d0 + r) * DD + k0 + cq + 8] = o1;
  } else {
    const int bb = b - 6400;        // 0..127 -> wcomb row 1024+bb
    const int k = t * 4;
    u16x4_t o;
    if (bb < 32) {
      const float* W = (bb < 16) ? WB : WC;
      const int n = bb & 15;
      #pragma unroll
      for (int j = 0; j < 4; ++j) o[j] = f2bf(W[(size_t)(k + j) * NS + n]);
    } else {
      o[0] = o[1] = o[2] = o[3] = 0;
    }
    *(u16x4_t*)&wcomb[(size_t)(1024 + bb) * DD + k] = o;
  }
}

// XshT[w][i*3+k] = xm[i][w-1+k] (zero-padded), bf16 -> bf16. out is [1024][3072].
__global__ __launch_bounds__(256) void build_xsht(const unsigned short* __restrict__ xm,
                                                  unsigned short* __restrict__ out) {
  __shared__ unsigned short Xs[64][66];
  const int t = threadIdx.x;
  const int w0 = blockIdx.x * 64, i0 = blockIdx.y * 64;
  {
    const int r = t >> 2, cq = (t & 3) << 4;
    #pragma unroll
    for (int c = 0; c < 16; c += 4) {
      u16x4_t v = *(const u16x4_t*)&xm[(size_t)(i0 + r) * DD + w0 + cq + c];
      Xs[r][1 + cq + c + 0] = v[0]; Xs[r][1 + cq + c + 1] = v[1];
      Xs[r][1 + cq + c + 2] = v[2]; Xs[r][1 + cq + c + 3] = v[3];
    }
  }
  if (t < 64)                 Xs[t][0]       = (w0 > 0)        ? xm[(size_t)(i0 + t) * DD + w0 - 1]  : (unsigned short)0;
  else if (t < 128) { int r = t - 64; Xs[r][65] = (w0 + 64 < DD) ? xm[(size_t)(i0 + r) * DD + w0 + 64] : (unsigned short)0; }
  __syncthreads();
  const int wr = t >> 2, q = t & 3;
  unsigned short vals[48];
  #pragma unroll
  for (int ii = 0; ii < 16; ++ii)
    #pragma unroll
    for (int k = 0; k < 3; ++k)
      vals[ii * 3 + k] = Xs[q * 16 + ii][wr + k];
  #pragma unroll
  for (int s = 0; s < 6; ++s) {
    u16x8_t o;
    #pragma unroll
    for (int j = 0; j < 8; ++j) o[j] = vals[s * 8 + j];
    *(u16x8_t*)&out[(size_t)(w0 + wr) * 3072 + (size_t)i0 * 3 + q * 48 + s * 8] = o;
  }
}

// ------------- bf16 MFMA GEMM: C = act(A[M,K] @ B[N,K]^T + bias) -------------
// 64x64 tile, BK=64, 4 waves (2x2) each 32x32 (2x2 frags, 8 MFMA/step).
// 3-buffer LDS; stage t+2 before compute t; counted vmcnt; raw barrier.
// Linear LDS dest; chunk ^ (row&7) swizzle on source+read (involution).
// PART: split-K slice blockIdx.z over Ksl columns -> fp32 partial (no act).
// ACT: 0 none, 1 silu, 2 softplus, 3 silu iff row>=1024, 4 softplus iff row<1024.
template<int ACT, bool BROW, bool O32, bool O16, bool PART>
__global__ __launch_bounds__(256) void gemm_bf16(
    const unsigned short* __restrict__ A, const unsigned short* __restrict__ B,
    const float* __restrict__ bias, float* __restrict__ C32,
    unsigned short* __restrict__ C16, int M, int N, int K, int Ksl,
    size_t sliceStride)
{
  constexpr int GI = 4;                  // glds per thread per stage
  __shared__ unsigned short s[3][128 * 64];
  const int tid  = threadIdx.x;
  const int lane = tid & 63;
  const int wv   = tid >> 6;
  const int wm   = wv >> 1, wn = wv & 1;
  const int m0 = blockIdx.y * 64, n0 = blockIdx.x * 64;
  const int wbase = tid & 192;  // wave-uniform
  const int koff = PART ? blockIdx.z * Ksl : 0;

  f32x4_t acc[2][2];
  #pragma unroll
  for (int i = 0; i < 2; ++i)
    #pragma unroll
    for (int j = 0; j < 2; ++j)
      acc[i][j] = (f32x4_t)(0.f);

  auto stage = [&](int buf, int kbase) {
    #pragma unroll
    for (int it = 0; it < GI; ++it) {
      const int c   = (it << 8) + tid;        // linear dest chunk id (0..1023)
      const int r   = c >> 3;                 // LDS row (64 A rows then 64 B rows)
      const int kcg = (c & 7) ^ (r & 7);      // pre-swizzled source k-chunk
      const unsigned short* src = (r < 64)
          ? (A + (size_t)(m0 + r) * K + kbase + kcg * 8)
          : (B + (size_t)(n0 + r - 64) * K + kbase + kcg * 8);
      __builtin_amdgcn_global_load_lds(
          (const __attribute__((address_space(1))) void*)src,
          (__attribute__((address_space(3))) void*)(&s[buf][0] + (size_t)((it << 8) + wbase) * 8),
          16, 0, 0);
    }
  };

  const int NT = Ksl >> 6;
  stage(0, koff);
  stage(1, koff + 64);
  s_wait_vmcnt<GI>();   // buf0 complete; buf1 in flight
  raw_barrier();

  for (int t = 0; t < NT; ++t) {
    if (t + 2 < NT) stage((t + 2) % 3, koff + (t + 2) * 64);

    const unsigned short* sb = &s[t % 3][0];
    const int rl = lane & 15, kq = lane >> 4;
    bf16x8_t af[2][2], bfr[2][2];
    #pragma unroll
    for (int mi = 0; mi < 2; ++mi) {
      const int row = wm * 32 + mi * 16 + rl;
      #pragma unroll
      for (int ks = 0; ks < 2; ++ks) {
        const int ch = row * 8 + ((ks * 4 + kq) ^ (row & 7));
        af[mi][ks] = *(const bf16x8_t*)(sb + (size_t)ch * 8);
      }
    }
    #pragma unroll
    for (int ni = 0; ni < 2; ++ni) {
      const int row = 64 + wn * 32 + ni * 16 + rl;
      #pragma unroll
      for (int ks = 0; ks < 2; ++ks) {
        const int ch = row * 8 + ((ks * 4 + kq) ^ (row & 7));
        bfr[ni][ks] = *(const bf16x8_t*)(sb + (size_t)ch * 8);
      }
    }
    #pragma unroll
    for (int mi = 0; mi < 2; ++mi)
      #pragma unroll
      for (int ni = 0; ni < 2; ++ni)
        #pragma unroll
        for (int ks = 0; ks < 2; ++ks)
          acc[mi][ni] = __builtin_amdgcn_mfma_f32_16x16x32_bf16(
              af[mi][ks], bfr[ni][ks], acc[mi][ni], 0, 0, 0);

    if (t + 1 < NT) {
      if (t + 2 < NT) s_wait_vmcnt<GI>();  // next buf ready, newest stays in flight
      else            s_wait_vmcnt<0>();
      raw_barrier();
    }
  }

  const int rl = lane & 15, rg = lane >> 4;
  float* outp = PART ? (C32 + (size_t)blockIdx.z * sliceStride) : C32;
  #pragma unroll
  for (int mi = 0; mi < 2; ++mi) {
    #pragma unroll
    for (int ni = 0; ni < 2; ++ni) {
      const int col = n0 + wn * 32 + ni * 16 + rl;
      #pragma unroll
      for (int j = 0; j < 4; ++j) {
        const int row = m0 + wm * 32 + mi * 16 + rg * 4 + j;
        float v = acc[mi][ni][j];
        if (PART) {
          outp[(size_t)row * N + col] = v;
        } else {
          if (bias) v += BROW ? bias[row] : bias[col];
          if (ACT == 1) v = silu_f(v);
          else if (ACT == 2) v = softplus_f(v);
          else if (ACT == 3) { if (row >= 1024) v = silu_f(v); }
          else if (ACT == 4) { if (row < 1024)  v = softplus_f(v); }
          if (O32) C32[(size_t)row * N + col] = v;
          if (O16) C16[(size_t)row * N + col] = f2bf(v);
        }
      }
    }
  }
}

// Conv reduce: sum 2 slices [1024][1024], +cb[row], silu; write xc16 [l][d]
// AND xcT32 [d][l] (transposed via LDS tile).
__global__ __launch_bounds__(256) void reduce_conv_t(
    const float* __restrict__ part, const float* __restrict__ cb,
    unsigned short* __restrict__ xc16, float* __restrict__ xcT)
{
  __shared__ float T[64][65];
  const int t = threadIdx.x;
  const int r = t >> 4;          // 0..15
  const int cq = (t & 15) << 2;  // 0..60
  const int r0 = blockIdx.y * 64, c0 = blockIdx.x * 64;
  #pragma unroll
  for (int rr = 0; rr < 64; rr += 16) {
    const int row = r0 + r + rr;
    const size_t base = (size_t)row * 1024 + c0 + cq;
    float4 s = *(const float4*)&part[base];
    const float4 p = *(const float4*)&part[(size_t)(1024 * 1024) + base];
    s.x += p.x; s.y += p.y; s.z += p.z; s.w += p.w;
    const float b = cb[row];
    float v[4] = {silu_f(s.x + b), silu_f(s.y + b), silu_f(s.z + b), silu_f(s.w + b)};
    u16x4_t o16; o16[0] = f2bf(v[0]); o16[1] = f2bf(v[1]);
    o16[2] = f2bf(v[2]); o16[3] = f2bf(v[3]);
    *(u16x4_t*)&xc16[base] = o16;
    T[r + rr][cq + 0] = v[0]; T[r + rr][cq + 1] = v[1];
    T[r + rr][cq + 2] = v[2]; T[r + rr][cq + 3] = v[3];
  }
  __syncthreads();
  #pragma unroll
  for (int rr = 0; rr < 64; rr += 16) {
    float4 o;
    o.x = T[cq + 0][r + rr]; o.y = T[cq + 1][r + rr];
    o.z = T[cq + 2][r + rr]; o.w = T[cq + 3][r + rr];
    *(float4*)&xcT[(size_t)(c0 + r + rr) * LL + r0 + cq] = o;
  }
}

// ---------------- chunk-parallel selective scan (2 kernels) ----------------
// Phase 1: per-chunk (prod Abar, local h) with h_in = 0.
__global__ __launch_bounds__(256) void scan_p1(
    const float* __restrict__ deltaT, const float* __restrict__ xcT,
    const float* __restrict__ BT, const float* __restrict__ A_log,
    float* __restrict__ P, float* __restrict__ H)
{
  const int tid = threadIdx.x;
  const int n = tid & 15, dl = tid >> 4;
  const int d = blockIdx.y * 16 + dl;
  const int c = blockIdx.x;
  const int l0 = c * CLEN;
  const float Av = -expf(A_log[d * NS + n]);
  float h = 0.f, p = 1.f;
  for (int j = 0; j < CLEN; j += 4) {
    const float4 dv = *(const float4*)&deltaT[(size_t)d * LL + l0 + j];
    const float4 xv = *(const float4*)&xcT[(size_t)d * LL + l0 + j];
    const float4 bv = *(const float4*)&BT[(size_t)n * LL + l0 + j];
    const float dvu[4] = {dv.x, dv.y, dv.z, dv.w};
    const float xvu[4] = {xv.x, xv.y, xv.z, xv.w};
    const float bvu[4] = {bv.x, bv.y, bv.z, bv.w};
    #pragma unroll
    for (int u = 0; u < 4; ++u) {
      const float ab = expf(dvu[u] * Av);
      h = fmaf(ab, h, dvu[u] * xvu[u] * bvu[u]);
      p *= ab;
    }
  }
  const int idx = d * NS + n;
  P[(size_t)c * (DD * NS) + idx] = p;
  H[(size_t)c * (DD * NS) + idx] = h;
}

// Phase 3 with in-block carry: h_in = prefix over chunks < c (<=15 fma from L2).
__global__ __launch_bounds__(256) void scan_p3c(
    const float* __restrict__ deltaT, const float* __restrict__ xcT,
    const float* __restrict__ BT, const float* __restrict__ CT,
    const float* __restrict__ P, const float* __restrict__ Hc,
    const float* __restrict__ A_log, unsigned short* __restrict__ y16)
{
  const int tid = threadIdx.x;
  const int n = tid & 15, dl = tid >> 4;
  const int d = blockIdx.y * 16 + dl;
  const int c = blockIdx.x;
  const int l0 = c * CLEN;
  const int idx = d * NS + n;
  const float Av = -expf(A_log[idx]);
  float h = 0.f;
  for (int cc = 0; cc < c; ++cc)
    h = fmaf(P[(size_t)cc * (DD * NS) + idx], h, Hc[(size_t)cc * (DD * NS) + idx]);
  for (int j = 0; j < CLEN; j += 4) {
    const float4 dv = *(const float4*)&deltaT[(size_t)d * LL + l0 + j];
    const float4 xv = *(const float4*)&xcT[(size_t)d * LL + l0 + j];
    const float4 bv = *(const float4*)&BT[(size_t)n * LL + l0 + j];
    const float4 cv = *(const float4*)&CT[(size_t)n * LL + l0 + j];
    const float dvu[4] = {dv.x, dv.y, dv.z, dv.w};
    const float xvu[4] = {xv.x, xv.y, xv.z, xv.w};
    const float bvu[4] = {bv.x, bv.y, bv.z, bv.w};
    const float cvu[4] = {cv.x, cv.y, cv.z, cv.w};
    #pragma unroll
    for (int u = 0; u < 4; ++u) {
      const int l = l0 + j + u;
      const float ab = expf(dvu[u] * Av);
      h = fmaf(ab, h, dvu[u] * xvu[u] * bvu[u]);
      float contrib = h * cvu[u];
      contrib += __shfl_xor(contrib, 1);
      contrib += __shfl_xor(contrib, 2);
      contrib += __shfl_xor(contrib, 4);
      contrib += __shfl_xor(contrib, 8);
      if (n == 0) y16[(size_t)l * DD + d] = f2bf(contrib);
    }
  }
}

// ---------------- launch (10 dispatches) ----------------
extern "C" void kernel_launch(void* const* d_in, const int* in_sizes, int n_in,
                              void* d_out, int out_size, void* d_ws, size_t ws_size,
                              hipStream_t stream) {
  const float* x       = (const float*)d_in[0];
  const float* W_proj  = (const float*)d_in[1];
  const float* b_proj  = (const float*)d_in[2];
  const float* conv_w  = (const float*)d_in[3];
  const float* conv_b  = (const float*)d_in[4];
  const float* A_log   = (const float*)d_in[5];
  const float* W_delta = (const float*)d_in[6];
  const float* W_B     = (const float*)d_in[7];
  const float* W_C     = (const float*)d_in[8];
  float* out = (float*)d_out;

  // Workspace: 0.25MB-granular offsets, peak 38.75 MB (< 46.75 proven).
  // Lifetime aliasing:
  //   [14.5,18.75) x16 (T0->T1) then dcomb32 (T4->scan), M=1088 rows exactly
  //   [18.75,24.75) cw16 (T0->T3) then y16 (p3c->T6), Pc/Hc (scan),
  //                 out116 (T6->T7, over Hc)
  //   part slab [30.75,38.75) used by conv split-K only.
  char* w = (char*)d_ws;
  const size_t QMB = 256 * 1024;  // 0.25 MB
  unsigned short* wp16    = (unsigned short*)(w);             // [0,2)
  unsigned short* pbuf    = (unsigned short*)(w + 8  * QMB);  // [2,6): xm16|xg16
  unsigned short* xm16    = pbuf;
  unsigned short* xg16    = pbuf + 1024 * 1024;
  unsigned short* wcomb16 = (unsigned short*)(w + 24 * QMB);  // [6,8.5) 1152 rows
  unsigned short* xc16    = (unsigned short*)(w + 34 * QMB);  // [8.5,10.5)
  float*          xcT32   = (float*)(w + 42 * QMB);           // [10.5,14.5)
  unsigned short* x16     = (unsigned short*)(w + 58 * QMB);  // [14.5,18.5)  T0->T1
  float*          dcomb32 = (float*)(w + 58 * QMB);           // [14.5,18.75) T4->scan
  float*          deltaT32= dcomb32;                          // rows 0..1023
  float*          BT32    = dcomb32 + (size_t)1024 * 1024;    // rows 1024..1039
  float*          CT32    = dcomb32 + (size_t)1040 * 1024;    // rows 1040..1055
  unsigned short* cw16    = (unsigned short*)(w + 75 * QMB);  // [18.75,24.75) T0->T3
  unsigned short* y16     = (unsigned short*)(w + 75 * QMB);  // [18.75,20.75) p3c->T6
  float*          Pc      = (float*)(w + 83 * QMB);           // [20.75,21.75) scan
  float*          Hc      = (float*)(w + 87 * QMB);           // [21.75,22.75) scan
  unsigned short* out116  = (unsigned short*)(w + 87 * QMB);  // [21.75,23.75) T6->T7
  unsigned short* xsht    = (unsigned short*)(w + 99 * QMB);  // [24.75,30.75) T2->T3
  float*          part    = (float*)(w + 123 * QMB);          // [30.75,38.75)
  (void)ws_size;

  const dim3 blk(256);

  // T0: all weight/input prep in one dispatch
  prep_all<<<dim3(6528), blk, 0, stream>>>(x, W_proj, conv_w, W_delta, W_B, W_C,
                                           x16, wp16, cw16, wcomb16);
  // T1 proj: p = x @ W_proj^T + b; rows>=1024 silu. Full K, 512 blocks.
  gemm_bf16<3, false, false, true, false><<<dim3(16, 32), blk, 0, stream>>>(
      x16, wp16, b_proj, nullptr, pbuf, 2048, 1024, 1024, 1024, 0);
  // T2 shifted-transposed conv activations
  build_xsht<<<dim3(16, 16), blk, 0, stream>>>(xm16, xsht);
  // T3 conv implicit GEMM, K=3072, SK=2 (512 blocks); reduce: +cb, silu, xc16+xcT
  gemm_bf16<0, false, true, false, true><<<dim3(16, 16, 2), blk, 0, stream>>>(
      cw16, xsht, nullptr, part, nullptr, 1024, 1024, 3072, 1536,
      (size_t)1024 * 1024);
  reduce_conv_t<<<dim3(16, 16), blk, 0, stream>>>(part, conv_b, xc16, xcT32);
  // T4 combined delta/B/C: wcomb rows 0..1087 @ xc^T, full K, fused softplus
  gemm_bf16<4, false, true, false, false><<<dim3(16, 17), blk, 0, stream>>>(
      wcomb16, xc16, nullptr, dcomb32, nullptr, 1088, 1024, 1024, 1024, 0);
  // T5 chunk-parallel scan (2 dispatches; p3 computes its own carry prefix)
  scan_p1<<<dim3(CCH, DD / 16), blk, 0, stream>>>(deltaT32, xcT32, BT32, A_log, Pc, Hc);
  scan_p3c<<<dim3(CCH, DD / 16), blk, 0, stream>>>(deltaT32, xcT32, BT32, CT32,
                                                   Pc, Hc, A_log, y16);
  // T6 out1 = y @ xg^T, full K, 256 blocks
  gemm_bf16<0, false, false, true, false><<<dim3(16, 16), blk, 0, stream>>>(
      y16, xg16, nullptr, nullptr, out116, 1024, 1024, 1024, 1024, 0);
  // T7 out = out1 @ W_proj^T + b, full K, 256 blocks
  gemm_bf16<0, false, true, false, false><<<dim3(16, 16), blk, 0, stream>>>(
      out116, wp16, b_proj, out, nullptr, 1024, 1024, 1024, 1024, 0);
}